// Round 3
// baseline (202.230 us; speedup 1.0000x reference)
//
#include <hip/hip_runtime.h>
#include <math.h>

static constexpr int H = 512;
static constexpr int B = 64;
static constexpr int P = 32;    // flash attention s-partitions
static constexpr int LSP = 32;  // log-softmax partitions

typedef __bf16 bf16x8 __attribute__((ext_vector_type(8)));
typedef __bf16 bf16x4 __attribute__((ext_vector_type(4)));
typedef float f32x4 __attribute__((ext_vector_type(4)));

__device__ __forceinline__ float sigmoidf_(float x) { return 1.f / (1.f + expf(-x)); }

// =====================================================================
// Fused GRU: computes all three gate GEMMs (r,z,n; PyTorch order) and the
// cell update in ONE kernel. Grid = H/64 blocks; block owns h-cols
// [c0, c0+64). 4 accumulator tile-sets share one A staging per K-step,
// identical wave/lane mapping -> epilogue is register-elementwise.
//   phase 0: A=embedded, W=w_ih  -> acc_r, acc_z, acc_n[0]
//   phase 1: A=hidden,   W=w_hh  -> acc_r, acc_z, acc_n[1]
//   h' = (1-z)*n + z*h0,  n = tanh(gin_i + r*gin_h)
// =====================================================================
__global__ __launch_bounds__(256) void gru_fused(
    const float* __restrict__ X, const float* __restrict__ Hp,
    const float* __restrict__ w_ih, const float* __restrict__ w_hh,
    const float* __restrict__ b_ih, const float* __restrict__ b_hh,
    float* __restrict__ hnew, float* __restrict__ combined)
{
    __shared__ __bf16 As[64 * 64];
    __shared__ __bf16 Wr[64 * 64];
    __shared__ __bf16 Wz[64 * 64];
    __shared__ __bf16 Wn[64 * 64];
    const int tid = threadIdx.x;
    const int lane = tid & 63;
    const int wv = tid >> 6;
    const int c0 = blockIdx.x * 64;
    const int lrow = tid >> 2;
    const int lq = tid & 3;
    const int ln = lane & 15;
    const int lk = (lane >> 4) << 3;

    f32x4 acc_r[4] = {}, acc_z[4] = {}, acc_n[2][4] = {};

    #pragma unroll
    for (int ph = 0; ph < 2; ++ph) {
        const float* a_src = ph ? Hp : X;
        const float* w_src = ph ? w_hh : w_ih;
        const float* Ap = a_src + (size_t)lrow * H + lq * 16;
        const float* Rp = w_src + (size_t)(c0 + lrow) * H + lq * 16;
        const float* Zp = w_src + (size_t)(H + c0 + lrow) * H + lq * 16;
        const float* Np = w_src + (size_t)(2 * H + c0 + lrow) * H + lq * 16;
        for (int t = 0; t < H / 64; ++t) {
            __syncthreads();   // prior MFMA reads done before overwrite
            #pragma unroll
            for (int i = 0; i < 4; ++i) {
                const int off = ((lrow << 6) + lq * 16 + 4 * i) ^ ((lrow & 7) << 3);
                const float4 va = *(const float4*)(Ap + t * 64 + 4 * i);
                const float4 vr = *(const float4*)(Rp + t * 64 + 4 * i);
                const float4 vz = *(const float4*)(Zp + t * 64 + 4 * i);
                const float4 vn = *(const float4*)(Np + t * 64 + 4 * i);
                *(bf16x4*)&As[off] = bf16x4{ (__bf16)va.x, (__bf16)va.y, (__bf16)va.z, (__bf16)va.w };
                *(bf16x4*)&Wr[off] = bf16x4{ (__bf16)vr.x, (__bf16)vr.y, (__bf16)vr.z, (__bf16)vr.w };
                *(bf16x4*)&Wz[off] = bf16x4{ (__bf16)vz.x, (__bf16)vz.y, (__bf16)vz.z, (__bf16)vz.w };
                *(bf16x4*)&Wn[off] = bf16x4{ (__bf16)vn.x, (__bf16)vn.y, (__bf16)vn.z, (__bf16)vn.w };
            }
            __syncthreads();
            bf16x8 br[2], bz[2], bn[2];
            #pragma unroll
            for (int ks = 0; ks < 2; ++ks) {
                const int row = wv * 16 + ln;
                const int off = ((row << 6) + ks * 32 + lk) ^ ((row & 7) << 3);
                br[ks] = *(bf16x8*)&Wr[off];
                bz[ks] = *(bf16x8*)&Wz[off];
                bn[ks] = *(bf16x8*)&Wn[off];
            }
            #pragma unroll
            for (int m = 0; m < 4; ++m) {
                const int row = m * 16 + ln;
                #pragma unroll
                for (int ks = 0; ks < 2; ++ks) {
                    const int off = ((row << 6) + ks * 32 + lk) ^ ((row & 7) << 3);
                    const bf16x8 af = *(bf16x8*)&As[off];
                    acc_r[m]     = __builtin_amdgcn_mfma_f32_16x16x32_bf16(af, br[ks], acc_r[m], 0, 0, 0);
                    acc_z[m]     = __builtin_amdgcn_mfma_f32_16x16x32_bf16(af, bz[ks], acc_z[m], 0, 0, 0);
                    acc_n[ph][m] = __builtin_amdgcn_mfma_f32_16x16x32_bf16(af, bn[ks], acc_n[ph][m], 0, 0, 0);
                }
            }
        }
    }

    const int h = c0 + wv * 16 + ln;
    const float br_ = b_ih[h] + b_hh[h];
    const float bz_ = b_ih[H + h] + b_hh[H + h];
    const float bni = b_ih[2 * H + h];
    const float bnh = b_hh[2 * H + h];
    #pragma unroll
    for (int m = 0; m < 4; ++m) {
        #pragma unroll
        for (int j = 0; j < 4; ++j) {
            const int b = m * 16 + (lane >> 4) * 4 + j;
            const float r = sigmoidf_(acc_r[m][j] + br_);
            const float z = sigmoidf_(acc_z[m][j] + bz_);
            const float n = tanhf(acc_n[0][m][j] + bni + r * (acc_n[1][m][j] + bnh));
            const float h0v = Hp[(size_t)b * H + h];
            const float hn = (1.f - z) * n + z * h0v;
            hnew[(size_t)b * H + h] = hn;
            combined[(size_t)b * 2 * H + h] = hn;
        }
    }
}

// =====================================================================
// fp32 tiled GEMM, W in [K][N] layout (bilinear: tmp = hnew @ bilin_w)
// =====================================================================
__global__ __launch_bounds__(256) void gemm_a64_kn(
    const float* __restrict__ A, const float* __restrict__ W,
    float* __restrict__ C, int K, int N, int ldc)
{
    __shared__ float As[64][68];
    __shared__ float Bs[64][68];
    const int tid = threadIdx.x;
    const int n0 = blockIdx.x * 64;
    const int tv = tid & 15;
    const int tb = tid >> 4;
    const int lrow = tid >> 2;
    const int lk0  = (tid & 3) * 16;

    float acc[4][4] = {{0.f, 0.f, 0.f, 0.f}};

    for (int kc = 0; kc < K; kc += 64) {
        #pragma unroll
        for (int i = 0; i < 4; ++i) {
            const float4 a = *(const float4*)(A + (size_t)lrow * K + kc + lk0 + 4 * i);
            As[lk0 + 4 * i + 0][lrow] = a.x;
            As[lk0 + 4 * i + 1][lrow] = a.y;
            As[lk0 + 4 * i + 2][lrow] = a.z;
            As[lk0 + 4 * i + 3][lrow] = a.w;
        }
        {
            const int v  = tid & 63;
            const int kg = tid >> 6;
            #pragma unroll
            for (int i = 0; i < 16; ++i) {
                const int kk = kg * 16 + i;
                Bs[kk][v] = (n0 + v < N) ? W[(size_t)(kc + kk) * N + n0 + v] : 0.f;
            }
        }
        __syncthreads();
        #pragma unroll 16
        for (int kk = 0; kk < 64; ++kk) {
            const float4 a = *(const float4*)&As[kk][tb * 4];
            const float4 b = *(const float4*)&Bs[kk][tv * 4];
            acc[0][0] += a.x * b.x; acc[0][1] += a.x * b.y; acc[0][2] += a.x * b.z; acc[0][3] += a.x * b.w;
            acc[1][0] += a.y * b.x; acc[1][1] += a.y * b.y; acc[1][2] += a.y * b.z; acc[1][3] += a.y * b.w;
            acc[2][0] += a.z * b.x; acc[2][1] += a.z * b.y; acc[2][2] += a.z * b.z; acc[2][3] += a.z * b.w;
            acc[3][0] += a.w * b.x; acc[3][1] += a.w * b.y; acc[3][2] += a.w * b.z; acc[3][3] += a.w * b.w;
        }
        __syncthreads();
    }
    #pragma unroll
    for (int i = 0; i < 4; ++i) {
        const int bb = tb * 4 + i;
        #pragma unroll
        for (int j = 0; j < 4; ++j) {
            const int n = n0 + tv * 4 + j;
            if (n < N) C[(size_t)bb * ldc + n] = acc[i][j];
        }
    }
}

// =====================================================================
// Flash attention partials: block (b, p), 1 wave. Online softmax over
// the s-subset {p, p+P, ...}: energy (raw, written out), running (m,l),
// unnormalized context accumulated in registers (8 floats/lane).
// =====================================================================
__global__ __launch_bounds__(64) void flash_part(
    const float* __restrict__ tmp, const float* __restrict__ enc,
    const float* __restrict__ bilin_b, float* __restrict__ energy,
    float* __restrict__ ctxp, float* __restrict__ mp, float* __restrict__ lp,
    int S)
{
    const int b = blockIdx.x;
    const int p = blockIdx.y;
    const int ln = threadIdx.x;
    const int k0 = ln * 8;

    const float4 t0 = *(const float4*)(tmp + (size_t)b * H + k0);
    const float4 t1 = *(const float4*)(tmp + (size_t)b * H + k0 + 4);
    const float bb = bilin_b[0];

    float m = -1e30f, l = 0.f;
    float4 c0 = {0.f, 0.f, 0.f, 0.f}, c1 = {0.f, 0.f, 0.f, 0.f};

    for (int s = p; s < S; s += P) {
        const float* e = enc + ((size_t)s * B + b) * H + k0;
        const float4 e0 = *(const float4*)(e);
        const float4 e1 = *(const float4*)(e + 4);
        float d = e0.x * t0.x + e0.y * t0.y + e0.z * t0.z + e0.w * t0.w
                + e1.x * t1.x + e1.y * t1.y + e1.z * t1.z + e1.w * t1.w;
        #pragma unroll
        for (int off = 32; off; off >>= 1) d += __shfl_xor(d, off);
        const float E = d + bb;
        if (ln == 0) energy[(size_t)s * B + b] = E;
        const float mn = fmaxf(m, E);
        const float sc = expf(m - mn);
        const float w  = expf(E - mn);
        l = l * sc + w;
        c0.x = c0.x * sc + w * e0.x; c0.y = c0.y * sc + w * e0.y;
        c0.z = c0.z * sc + w * e0.z; c0.w = c0.w * sc + w * e0.w;
        c1.x = c1.x * sc + w * e1.x; c1.y = c1.y * sc + w * e1.y;
        c1.z = c1.z * sc + w * e1.z; c1.w = c1.w * sc + w * e1.w;
        m = mn;
    }
    float* cp = ctxp + ((size_t)b * P + p) * H + k0;
    *(float4*)cp = c0;
    *(float4*)(cp + 4) = c1;
    if (ln == 0) { mp[b * P + p] = m; lp[b * P + p] = l; }
}

// =====================================================================
// Combine flash partials: global (M,L) per b, context -> combined[:,H:],
// attn[s][b] = exp(energy - M)/L -> d_out.
// =====================================================================
__global__ __launch_bounds__(256) void attn_combine(
    const float* __restrict__ mp, const float* __restrict__ lp,
    const float* __restrict__ ctxp, const float* __restrict__ energy,
    float* __restrict__ combined, float* __restrict__ attn, int S)
{
    const int b = blockIdx.x;
    const int t = threadIdx.x;
    __shared__ float sm_[P], sl_[P], sc_[P];
    if (t < P) { sm_[t] = mp[b * P + t]; sl_[t] = lp[b * P + t]; }
    __syncthreads();
    float M = -1e30f;
    #pragma unroll
    for (int p = 0; p < P; ++p) M = fmaxf(M, sm_[p]);
    if (t < P) sc_[t] = expf(sm_[t] - M);
    __syncthreads();
    float L = 0.f;
    #pragma unroll
    for (int p = 0; p < P; ++p) L += sl_[p] * sc_[p];
    const float invL = 1.f / L;

    for (int h = t; h < H; h += 256) {
        float acc = 0.f;
        #pragma unroll
        for (int p = 0; p < P; ++p)
            acc += ctxp[((size_t)b * P + p) * H + h] * sc_[p];
        combined[(size_t)b * 2 * H + H + h] = acc * invL;
    }
    for (int s = t; s < S; s += 256)
        attn[(size_t)s * B + b] = expf(energy[(size_t)s * B + b] - M) * invL;
}

// =====================================================================
// bf16-MFMA GEMM, tile 64M x 128N x 64K: logits = combined @ out_w^T + b
// Wave owns 32 N-cols (2 frags). Double-buffered swizzled LDS,
// register prefetch issued between barrier and MFMA.
// =====================================================================
__global__ __launch_bounds__(256) void gemm_mfma_nt128(
    const float* __restrict__ A,   // [64][K]
    const float* __restrict__ W,   // [N][K]
    const float* __restrict__ bias,
    float* __restrict__ C, int K, int N, int ldc)
{
    __shared__ __bf16 As[2][64 * 64];
    __shared__ __bf16 Ws[2][128 * 64];

    const int tid = threadIdx.x;
    const int lane = tid & 63;
    const int wv = tid >> 6;
    const int n0 = blockIdx.x * 128;

    const int arow = tid >> 2, aq = tid & 3;   // A: 64 rows x 4 quarters
    const int wrow = tid >> 1, wh = tid & 1;   // W: 128 rows x 2 halves
    int wr = n0 + wrow;
    if (wr > N - 1) wr = N - 1;
    const float* Aptr = A + (size_t)arow * K + aq * 16;
    const float* Wptr = W + (size_t)wr * K + wh * 32;

    f32x4 acc[4][2] = {};
    float4 ra[4], rw[8];
    #pragma unroll
    for (int i = 0; i < 4; ++i) ra[i] = *(const float4*)(Aptr + 4 * i);
    #pragma unroll
    for (int i = 0; i < 8; ++i) rw[i] = *(const float4*)(Wptr + 4 * i);

    const int ln = lane & 15;
    const int lk = (lane >> 4) << 3;
    const int NT = K >> 6;

    for (int t = 0; t < NT; ++t) {
        __bf16* a_s = As[t & 1];
        __bf16* w_s = Ws[t & 1];
        #pragma unroll
        for (int i = 0; i < 4; ++i) {
            const int off = ((arow << 6) + aq * 16 + 4 * i) ^ ((arow & 7) << 3);
            *(bf16x4*)&a_s[off] = bf16x4{ (__bf16)ra[i].x, (__bf16)ra[i].y, (__bf16)ra[i].z, (__bf16)ra[i].w };
        }
        #pragma unroll
        for (int i = 0; i < 8; ++i) {
            const int off = ((wrow << 6) + wh * 32 + 4 * i) ^ ((wrow & 7) << 3);
            *(bf16x4*)&w_s[off] = bf16x4{ (__bf16)rw[i].x, (__bf16)rw[i].y, (__bf16)rw[i].z, (__bf16)rw[i].w };
        }
        __syncthreads();
        if (t + 1 < NT) {
            const float* Ap = Aptr + (t + 1) * 64;
            const float* Wp = Wptr + (t + 1) * 64;
            #pragma unroll
            for (int i = 0; i < 4; ++i) ra[i] = *(const float4*)(Ap + 4 * i);
            #pragma unroll
            for (int i = 0; i < 8; ++i) rw[i] = *(const float4*)(Wp + 4 * i);
        }
        bf16x8 bfrag[2][2];
        #pragma unroll
        for (int nf = 0; nf < 2; ++nf) {
            #pragma unroll
            for (int ks = 0; ks < 2; ++ks) {
                const int row = wv * 32 + nf * 16 + ln;
                const int off = ((row << 6) + ks * 32 + lk) ^ ((row & 7) << 3);
                bfrag[nf][ks] = *(bf16x8*)&w_s[off];
            }
        }
        #pragma unroll
        for (int m = 0; m < 4; ++m) {
            const int row = m * 16 + ln;
            #pragma unroll
            for (int ks = 0; ks < 2; ++ks) {
                const int off = ((row << 6) + ks * 32 + lk) ^ ((row & 7) << 3);
                const bf16x8 af = *(bf16x8*)&a_s[off];
                #pragma unroll
                for (int nf = 0; nf < 2; ++nf)
                    acc[m][nf] = __builtin_amdgcn_mfma_f32_16x16x32_bf16(af, bfrag[nf][ks], acc[m][nf], 0, 0, 0);
            }
        }
    }

    #pragma unroll
    for (int nf = 0; nf < 2; ++nf) {
        const int col = n0 + wv * 32 + nf * 16 + ln;
        if (col < N) {
            const float bv = bias[col];
            #pragma unroll
            for (int m = 0; m < 4; ++m) {
                const int rbase = m * 16 + (lane >> 4) * 4;
                #pragma unroll
                for (int j = 0; j < 4; ++j)
                    C[(size_t)(rbase + j) * ldc + col] = acc[m][nf][j] + bv;
            }
        }
    }
}

// =====================================================================
// log_softmax, 3-stage
// =====================================================================
__global__ __launch_bounds__(256) void lsm_part(
    const float* __restrict__ logits, float* __restrict__ pm,
    float* __restrict__ ps, int V)
{
    const int b = blockIdx.x;
    const int p = blockIdx.y;
    const int t = threadIdx.x;
    const int V4 = V >> 2;
    const int chunk = (V4 + LSP - 1) / LSP;
    const int i0 = p * chunk;
    int i1 = i0 + chunk; if (i1 > V4) i1 = V4;
    const float4* row = (const float4*)(logits + (size_t)b * V);
    __shared__ float sm[4], ss[4];

    float m = -1e30f;
    for (int i = i0 + t; i < i1; i += 256) {
        const float4 v = row[i];
        m = fmaxf(fmaxf(fmaxf(m, v.x), v.y), fmaxf(v.z, v.w));
    }
    #pragma unroll
    for (int off = 32; off; off >>= 1) m = fmaxf(m, __shfl_xor(m, off));
    if ((t & 63) == 0) sm[t >> 6] = m;
    __syncthreads();
    m = fmaxf(fmaxf(sm[0], sm[1]), fmaxf(sm[2], sm[3]));

    float s = 0.f;
    for (int i = i0 + t; i < i1; i += 256) {
        const float4 v = row[i];
        s += expf(v.x - m) + expf(v.y - m) + expf(v.z - m) + expf(v.w - m);
    }
    #pragma unroll
    for (int off = 32; off; off >>= 1) s += __shfl_xor(s, off);
    if ((t & 63) == 0) ss[t >> 6] = s;
    __syncthreads();
    if (t == 0) {
        pm[b * LSP + p] = m;
        ps[b * LSP + p] = ss[0] + ss[1] + ss[2] + ss[3];
    }
}

__global__ __launch_bounds__(64) void lsm_combine(
    const float* __restrict__ pm, const float* __restrict__ ps,
    float* __restrict__ c)
{
    const int b = blockIdx.x;
    const int l = threadIdx.x;
    float m = (l < LSP) ? pm[b * LSP + l] : -1e30f;
    float mm = m;
    #pragma unroll
    for (int off = 32; off; off >>= 1) mm = fmaxf(mm, __shfl_xor(mm, off));
    float s = (l < LSP) ? ps[b * LSP + l] * expf(m - mm) : 0.f;
    #pragma unroll
    for (int off = 32; off; off >>= 1) s += __shfl_xor(s, off);
    if (l == 0) c[b] = mm + logf(s);
}

__global__ __launch_bounds__(256) void lsm_apply(
    float* __restrict__ logits, const float* __restrict__ c, int V)
{
    const int b = blockIdx.y;
    const int i = blockIdx.x * 256 + threadIdx.x;
    const int V4 = V >> 2;
    if (i >= V4) return;
    float4* row = (float4*)(logits + (size_t)b * V);
    float4 v = row[i];
    const float cb = c[b];
    v.x -= cb; v.y -= cb; v.z -= cb; v.w -= cb;
    row[i] = v;
}

// =====================================================================
extern "C" void kernel_launch(void* const* d_in, const int* in_sizes, int n_in,
                              void* d_out, int out_size, void* d_ws, size_t ws_size,
                              hipStream_t stream)
{
    const float* embedded = (const float*)d_in[0];
    const float* hidden   = (const float*)d_in[1];
    const float* enc      = (const float*)d_in[2];
    const float* w_ih     = (const float*)d_in[3];
    const float* w_hh     = (const float*)d_in[4];
    const float* b_ih     = (const float*)d_in[5];
    const float* b_hh     = (const float*)d_in[6];
    const float* bilin_w  = (const float*)d_in[7];
    const float* bilin_b  = (const float*)d_in[8];
    const float* out_w    = (const float*)d_in[9];
    const float* out_b    = (const float*)d_in[10];
    float* out = (float*)d_out;

    const int S = in_sizes[2] / (B * H);      // 400
    const int V = in_sizes[9] / (2 * H);      // 50000

    float* logp = out;
    float* hnew = out + (size_t)B * V;
    float* attn = hnew + (size_t)B * H;

    float* ws       = (float*)d_ws;
    float* tmp      = ws;                         // B*H
    float* energy   = tmp + (size_t)B * H;        // S*B
    float* combined = energy + (size_t)S * B;     // B*2H
    float* ctxp     = combined + (size_t)B * 2 * H; // B*P*H
    float* mp       = ctxp + (size_t)B * P * H;   // B*P
    float* lp       = mp + (size_t)B * P;         // B*P
    float* pm       = lp + (size_t)B * P;         // B*LSP
    float* ps       = pm + (size_t)B * LSP;       // B*LSP
    float* cb       = ps + (size_t)B * LSP;       // B

    // 1) fused GRU -> hnew (d_out) + combined[:, :H]
    gru_fused<<<H / 64, 256, 0, stream>>>(embedded, hidden, w_ih, w_hh, b_ih, b_hh, hnew, combined);

    // 2) tmp = hnew @ bilin_w[0]
    gemm_a64_kn<<<H / 64, 256, 0, stream>>>(hnew, bilin_w, tmp, H, H, H);

    // 3) flash attention partials (one pass over enc)
    flash_part<<<dim3(B, P), 64, 0, stream>>>(tmp, enc, bilin_b, energy, ctxp, mp, lp, S);

    // 4) combine -> combined[:, H:] and attn (d_out)
    attn_combine<<<B, 256, 0, stream>>>(mp, lp, ctxp, energy, combined, attn, S);

    // 5) logits = combined @ out_w^T + out_b
    gemm_mfma_nt128<<<(V + 127) / 128, 256, 0, stream>>>(combined, out_w, out_b, logp, 2 * H, V, V);

    // 6) log_softmax
    lsm_part<<<dim3(B, LSP), 256, 0, stream>>>(logp, pm, ps, V);
    lsm_combine<<<B, 64, 0, stream>>>(pm, ps, cb);
    lsm_apply<<<dim3((V / 4 + 255) / 256, B), 256, 0, stream>>>(logp, cb, V);
}